// Round 10
// baseline (2901.587 us; speedup 1.0000x reference)
//
#include <hip/hip_runtime.h>
#include <math.h>

#define F   128
#define H   64
#define HH  32
#define RG  4

typedef __bf16         bf16x8 __attribute__((ext_vector_type(8)));
typedef short          s16x8  __attribute__((ext_vector_type(8)));
typedef float          f32x4  __attribute__((ext_vector_type(4)));

// Scalar split: w = hi + lo, both bf16 (scalar casts only).
__device__ __forceinline__ void bf16_split(float w, unsigned short& hi,
                                           unsigned short& lo) {
    __bf16 hb = (__bf16)w;
    float hif = (float)hb;
    __bf16 lb = (__bf16)(w - hif);
    hi = __builtin_bit_cast(unsigned short, hb);
    lo = __builtin_bit_cast(unsigned short, lb);
}

// ---------------------------------------------------------------------------
// Prep: unchanged from Round 7 (W2F packed but unused this round — keeps ws
// layout/sig_emb offset identical; minimal diff for the bisection).
// ---------------------------------------------------------------------------
__global__ void prep_weights(const float* __restrict__ W1,
                             const float* __restrict__ W2,
                             const float* __restrict__ emb,
                             unsigned short* __restrict__ W1F_hi,
                             unsigned short* __restrict__ W1F_lo,
                             unsigned short* __restrict__ W2F_hi,
                             unsigned short* __restrict__ W2F_lo,
                             float* __restrict__ sig_emb) {
    int t = blockIdx.x * blockDim.x + threadIdx.x;
    if (t < H * F) {
        int i = t & 7, lane = (t >> 3) & 63, nt = (t >> 9) & 3, kb = t >> 11;
        int k   = kb * 32 + (lane >> 4) * 8 + i;
        int col = nt * 16 + (lane & 15);
        unsigned short hi, lo;
        bf16_split(W1[col * F + k], hi, lo);           // W1T[k][col]
        W1F_hi[t] = hi; W1F_lo[t] = lo;
    } else if (t < H * F + H * HH) {
        int t2 = t - H * F;
        int i = t2 & 7, lane = (t2 >> 3) & 63, nt = (t2 >> 9) & 1, kb = (t2 >> 10) & 1;
        int k   = kb * 32 + (lane >> 4) * 8 + i;
        int col = nt * 16 + (lane & 15);
        unsigned short hi, lo;
        bf16_split(W2[col * H + k], hi, lo);
        W2F_hi[t2] = hi; W2F_lo[t2] = lo;
    } else if (t < H * F + H * HH + RG * HH) {
        int t3 = t - (H * F + H * HH);
        sig_emb[t3] = 1.0f / (1.0f + expf(-emb[t3]));
    }
}

__device__ __forceinline__ float gelu_exact(float v) {
    return 0.5f * v * (1.0f + erff(v * 0.70710678118654752440f));
}

__device__ __forceinline__ f32x4 mfma_bf16(s16x8 a, s16x8 b, f32x4 c) {
    return __builtin_amdgcn_mfma_f32_16x16x32_bf16(
        __builtin_bit_cast(bf16x8, a), __builtin_bit_cast(bf16x8, b), c, 0, 0, 0);
}

// ---------------------------------------------------------------------------
// BISECTION KERNEL (Round 10):
//   Layer 1: MFMA + hi/lo 4-term split + LN in D-layout  [UNDER TEST]
//   Bridge:  fp32 LDS (no bf16 re-split)                 [removed from budget]
//   Layer 2 + heads: fp32 VALU, fallback-kernel math     [KNOWN GOOD]
// PASS -> L1 path sound, bug was in L2 MFMA/bounce. FAIL -> L1 split/frag.
// ---------------------------------------------------------------------------
__global__ __launch_bounds__(256, 2)
void fused_bisect(const float* __restrict__ x,
                  const int*   __restrict__ regime,
                  const unsigned short* __restrict__ W1F_hi,
                  const unsigned short* __restrict__ W1F_lo,
                  const float* __restrict__ W2,       // fp32 [HH][H] original
                  const float* __restrict__ b1,
                  const float* __restrict__ gamma,
                  const float* __restrict__ beta,
                  const float* __restrict__ b2,
                  const float* __restrict__ Wg,       // [2][HH]
                  const float* __restrict__ bg,       // [2]
                  const float* __restrict__ Wr,       // [RG][2][HH]
                  const float* __restrict__ br,       // [RG][2]
                  const float* __restrict__ sig_emb,  // [RG][HH]
                  const float* __restrict__ log_temp,
                  float* __restrict__ out,
                  int B) {
    // [sample][feature] fp32; 68-word row stride = 272 B (16B-aligned, padded)
    __shared__ float hbuf[4][16][68];

    const int tid  = threadIdx.x;
    const int wave = tid >> 6;
    const int lane = tid & 63;
    const int lr   = lane & 15;   // C/D col | A row
    const int lg   = lane >> 4;   // k-group

    const int rowbase = blockIdx.x * 64 + wave * 16;

    const s16x8* B1h = (const s16x8*)W1F_hi;
    const s16x8* B1l = (const s16x8*)W1F_lo;

    // ---- Layer 1: 16x64 C-tile, K=128, hi/lo 4-term MFMA -----------------
    f32x4 acc[4] = {};                      // acc[nt][reg]
    int xrow = rowbase + lr; if (xrow >= B) xrow = B - 1;
    const float* xp = x + (size_t)xrow * F + lg * 8;

#pragma unroll
    for (int kb = 0; kb < 4; ++kb) {
        float4 a0 = *(const float4*)(xp + kb * 32);
        float4 a1 = *(const float4*)(xp + kb * 32 + 4);
        float av[8] = {a0.x, a0.y, a0.z, a0.w, a1.x, a1.y, a1.z, a1.w};
        s16x8 ah, al;
#pragma unroll
        for (int i = 0; i < 8; ++i) {
            unsigned short hi, lo;
            bf16_split(av[i], hi, lo);
            ah[i] = (short)hi;
            al[i] = (short)lo;
        }
#pragma unroll
        for (int nt = 0; nt < 4; ++nt) {
            s16x8 bh = B1h[(kb * 4 + nt) * 64 + lane];
            s16x8 bl = B1l[(kb * 4 + nt) * 64 + lane];
            acc[nt] = mfma_bf16(ah, bh, acc[nt]);
            acc[nt] = mfma_bf16(al, bh, acc[nt]);
            acc[nt] = mfma_bf16(ah, bl, acc[nt]);
            acc[nt] = mfma_bf16(al, bl, acc[nt]);
        }
    }

    // ---- bias + LayerNorm + GELU in D-layout; fp32 to LDS ----------------
    float b1v[4], gv[4], bev[4];
#pragma unroll
    for (int nt = 0; nt < 4; ++nt) {
        b1v[nt] = b1[lr + 16 * nt];
        gv[nt]  = gamma[lr + 16 * nt];
        bev[nt] = beta[lr + 16 * nt];
    }

#pragma unroll
    for (int reg = 0; reg < 4; ++reg) {     // sample = lg*4 + reg
        float s = 0.f, ss = 0.f;
#pragma unroll
        for (int nt = 0; nt < 4; ++nt) {
            float v = acc[nt][reg] + b1v[nt];
            acc[nt][reg] = v;
            s += v; ss += v * v;
        }
#pragma unroll
        for (int m = 1; m < 16; m <<= 1) {  // reduce over lr (16 lanes)
            s  += __shfl_xor(s, m);
            ss += __shfl_xor(ss, m);
        }
        float mu   = s * (1.0f / 64.0f);
        float var  = ss * (1.0f / 64.0f) - mu * mu;
        float rstd = rsqrtf(var + 1e-5f);
#pragma unroll
        for (int nt = 0; nt < 4; ++nt) {
            float v = fmaf(gv[nt], (acc[nt][reg] - mu) * rstd, bev[nt]);
            hbuf[wave][lg * 4 + reg][lr + 16 * nt] = gelu_exact(v);
        }
    }

    __syncthreads();   // LDS visibility across lanes (cheap: uniform work)

    // ---- Layer 2 + heads: fp32 VALU (fallback math) ----------------------
    // 4 lanes per sample: samp = lane>>2 (0..15), oblk = lane&3 (8 outputs).
    const int samp = lane >> 2;
    const int oblk = lane & 3;

    float h2a[8];
#pragma unroll
    for (int o8 = 0; o8 < 8; ++o8) h2a[o8] = b2[oblk * 8 + o8];

    for (int k4 = 0; k4 < H / 4; ++k4) {    // runtime loop: LDS/global only
        float4 hv = *(const float4*)&hbuf[wave][samp][k4 * 4];
#pragma unroll
        for (int o8 = 0; o8 < 8; ++o8) {
            const float* w = W2 + (oblk * 8 + o8) * H + k4 * 4;
            float4 wv = *(const float4*)w;
            h2a[o8] = fmaf(hv.x, wv.x,
                      fmaf(hv.y, wv.y,
                      fmaf(hv.z, wv.z,
                      fmaf(hv.w, wv.w, h2a[o8]))));
        }
    }

    float h2v[8];
#pragma unroll
    for (int o8 = 0; o8 < 8; ++o8) h2v[o8] = gelu_exact(h2a[o8]);

    int grow = rowbase + samp;              // < B always (B multiple of 64)
    int rr   = regime[grow];
    const float* wrp = Wr + rr * 64;        // [2][32] slice
    const float* gep = sig_emb + rr * 32;

    float p0 = 0.f, p1 = 0.f, p2 = 0.f, p3 = 0.f, p4 = 0.f, p5 = 0.f;
#pragma unroll
    for (int o8 = 0; o8 < 8; ++o8) {
        int k = oblk * 8 + o8;
        float hv = h2v[o8];
        float hg = hv * gep[k];
        p0 = fmaf(Wg[k],      hv, p0);
        p1 = fmaf(Wg[HH + k], hv, p1);
        p2 = fmaf(wrp[k],      hv, p2);
        p3 = fmaf(wrp[HH + k], hv, p3);
        p4 = fmaf(Wg[k],      hg, p4);
        p5 = fmaf(Wg[HH + k], hg, p5);
    }
#pragma unroll
    for (int m = 1; m < 4; m <<= 1) {       // reduce over the 4 oblk lanes
        p0 += __shfl_xor(p0, m);
        p1 += __shfl_xor(p1, m);
        p2 += __shfl_xor(p2, m);
        p3 += __shfl_xor(p3, m);
        p4 += __shfl_xor(p4, m);
        p5 += __shfl_xor(p5, m);
    }

    if (oblk == 0) {
        float temp = expf(log_temp[0]);
        temp = fminf(fmaxf(temp, 0.5f), 5.0f);
        float inv_t = 1.0f / temp;
        float g0 = p0 + bg[0],      g1 = p1 + bg[1];
        float r0 = p2 + br[rr * 2], r1 = p3 + br[rr * 2 + 1];
        float q0 = p4 + bg[0],      q1 = p5 + bg[1];
        float2 res;
        res.x = (0.5f * g0 + 0.3f * r0 + 0.2f * q0) * inv_t;
        res.y = (0.5f * g1 + 0.3f * r1 + 0.2f * q1) * inv_t;
        *(float2*)(out + (size_t)grow * 2) = res;
    }
}

// ---------------------------------------------------------------------------
// Fallback (ws too small): Round-2 thread-per-row VALU kernel. Known-good.
// ---------------------------------------------------------------------------
__global__ __launch_bounds__(256, 2)
void fused_fallback(const float* __restrict__ x, const int* __restrict__ regime,
                    const float* __restrict__ W1, const float* __restrict__ b1,
                    const float* __restrict__ gamma, const float* __restrict__ beta,
                    const float* __restrict__ W2, const float* __restrict__ b2,
                    const float* __restrict__ Wg, const float* __restrict__ bg,
                    const float* __restrict__ Wr, const float* __restrict__ br,
                    const float* __restrict__ emb, const float* __restrict__ log_temp,
                    float* __restrict__ out, int B) {
    int row = blockIdx.x * blockDim.x + threadIdx.x;
    if (row >= B) return;
    const float4* x4 = reinterpret_cast<const float4*>(x + (size_t)row * F);
    float h[H];
#pragma unroll
    for (int j = 0; j < H; ++j) h[j] = b1[j];
    for (int f4 = 0; f4 < F / 4; ++f4) {
        float4 xv = x4[f4];
#pragma unroll
        for (int j = 0; j < H; ++j) {
            const float* w = W1 + j * F + f4 * 4;
            h[j] = fmaf(xv.x, w[0], fmaf(xv.y, w[1], fmaf(xv.z, w[2], fmaf(xv.w, w[3], h[j]))));
        }
    }
    float mu = 0.f;
#pragma unroll
    for (int j = 0; j < H; ++j) mu += h[j];
    mu *= (1.0f / H);
    float var = 0.f;
#pragma unroll
    for (int j = 0; j < H; ++j) { float d = h[j] - mu; var = fmaf(d, d, var); }
    var *= (1.0f / H);
    float rstd = rsqrtf(var + 1e-5f);
#pragma unroll
    for (int j = 0; j < H; ++j)
        h[j] = gelu_exact(fmaf(gamma[j], (h[j] - mu) * rstd, beta[j]));
    float h2[HH];
#pragma unroll 4
    for (int k = 0; k < HH; ++k) {
        const float* w = W2 + k * H;
        float a = b2[k];
#pragma unroll
        for (int j = 0; j < H; ++j) a = fmaf(h[j], w[j], a);
        h2[k] = gelu_exact(a);
    }
    int reg = regime[row];
    const float* wr = Wr + reg * 2 * HH;
    const float* e  = emb + reg * HH;
    float g0 = bg[0], g1 = bg[1], r0 = br[reg * 2], r1 = br[reg * 2 + 1];
    float q0 = bg[0], q1 = bg[1];
#pragma unroll
    for (int k = 0; k < HH; ++k) {
        float hv = h2[k];
        float gk = 1.0f / (1.0f + expf(-e[k]));
        float hg = hv * gk;
        g0 = fmaf(Wg[k], hv, g0);  g1 = fmaf(Wg[HH + k], hv, g1);
        r0 = fmaf(wr[k], hv, r0);  r1 = fmaf(wr[HH + k], hv, r1);
        q0 = fmaf(Wg[k], hg, q0);  q1 = fmaf(Wg[HH + k], hg, q1);
    }
    float temp = expf(log_temp[0]);
    temp = fminf(fmaxf(temp, 0.5f), 5.0f);
    float inv_t = 1.0f / temp;
    float2 res;
    res.x = (0.5f * g0 + 0.3f * r0 + 0.2f * q0) * inv_t;
    res.y = (0.5f * g1 + 0.3f * r1 + 0.2f * q1) * inv_t;
    reinterpret_cast<float2*>(out)[row] = res;
}

extern "C" void kernel_launch(void* const* d_in, const int* in_sizes, int n_in,
                              void* d_out, int out_size, void* d_ws, size_t ws_size,
                              hipStream_t stream) {
    const float* x      = (const float*)d_in[0];
    const int*   regime = (const int*)  d_in[1];
    const float* W1     = (const float*)d_in[2];
    const float* b1     = (const float*)d_in[3];
    const float* gamma  = (const float*)d_in[4];
    const float* beta   = (const float*)d_in[5];
    const float* W2     = (const float*)d_in[6];
    const float* b2     = (const float*)d_in[7];
    const float* Wg     = (const float*)d_in[8];
    const float* bg     = (const float*)d_in[9];
    const float* Wr     = (const float*)d_in[10];
    const float* br     = (const float*)d_in[11];
    const float* emb    = (const float*)d_in[12];
    const float* lt     = (const float*)d_in[13];
    float*       out    = (float*)d_out;

    int B = in_sizes[0] / F;

    // ws layout (u16): W1F_hi[8192] W1F_lo[8192] W2F_hi[2048] W2F_lo[2048],
    // then sig_emb[128] f32  => 41472 bytes
    size_t need = (size_t)(H * F + H * HH) * 2 * 2 + RG * HH * 4;
    if (ws_size >= need) {
        unsigned short* W1F_hi = (unsigned short*)d_ws;
        unsigned short* W1F_lo = W1F_hi + H * F;
        unsigned short* W2F_hi = W1F_lo + H * F;
        unsigned short* W2F_lo = W2F_hi + H * HH;
        float*          sig    = (float*)(W2F_lo + H * HH);

        int prep_n = H * F + H * HH + RG * HH;
        prep_weights<<<dim3((prep_n + 255) / 256), dim3(256), 0, stream>>>(
            W1, W2, emb, W1F_hi, W1F_lo, W2F_hi, W2F_lo, sig);

        int blocks = (B + 63) / 64;
        fused_bisect<<<dim3(blocks), dim3(256), 0, stream>>>(
            x, regime, W1F_hi, W1F_lo, W2,
            b1, gamma, beta, b2, Wg, bg, Wr, br, sig, lt, out, B);
    } else {
        int blocks = (B + 255) / 256;
        fused_fallback<<<dim3(blocks), dim3(256), 0, stream>>>(
            x, regime, W1, b1, gamma, beta, W2, b2, Wg, bg, Wr, br, emb, lt,
            out, B);
    }
}